// Round 12
// baseline (619.642 us; speedup 1.0000x reference)
//
#include <hip/hip_runtime.h>
#include <cstdint>
#include <cstddef>

typedef __bf16 bf16_t;
typedef __bf16 bf16x4 __attribute__((ext_vector_type(4)));
typedef __bf16 bf16x8 __attribute__((ext_vector_type(8)));
typedef float f32x4 __attribute__((ext_vector_type(4)));

#define B_ 4
#define T_ 2048
#define DIM_ 2048
#define H_ 16
#define KVH_ 4
#define HD_ 128
#define QKV_ 3072
// SCALE * log2(e): folded into q rows in the gemm_qkv epilogue; attn uses exp2.
#define QSCALE (0.08838834764831845f * 1.4426950408889634f)

// ---------------------------------------------------------------------------
// async global->LDS, 16B per lane. LDS dest = wave-uniform base + lane*16B.
// Dest pointer arithmetic is in ELEMENTS: 8 bf16 = 16B per lane.
// ---------------------------------------------------------------------------
__device__ __forceinline__ void gload16(const bf16_t* g, bf16_t* l) {
  __builtin_amdgcn_global_load_lds(
      (const __attribute__((address_space(1))) unsigned int*)g,
      (__attribute__((address_space(3))) unsigned int*)l, 16, 0, 0);
}

// ---------------------------------------------------------------------------
// fused fp32 -> bf16 convert for all five inputs (one launch).
// ---------------------------------------------------------------------------
__global__ __launch_bounds__(256) void cvt_all(const float4* __restrict__ x,
                                               const float4* __restrict__ wq,
                                               const float4* __restrict__ wk,
                                               const float4* __restrict__ wv,
                                               const float4* __restrict__ wp,
                                               bf16x4* __restrict__ xb,
                                               bf16x4* __restrict__ wqkvb,
                                               bf16x4* __restrict__ wpb) {
  int i = blockIdx.x * 256 + threadIdx.x;
  const float4* s;
  bf16x4* dst;
  int off;
  if (i < 4194304) { s = x; dst = xb; off = i; }
  else if (i < 5242880) { s = wq; dst = wqkvb; off = i - 4194304; }
  else if (i < 5505024) { s = wk; dst = wqkvb + 1048576; off = i - 5242880; }
  else if (i < 5767168) { s = wv; dst = wqkvb + 1310720; off = i - 5505024; }
  else { s = wp; dst = wpb; off = i - 5767168; }
  float4 v = s[off];
  bf16x4 o = {(__bf16)v.x, (__bf16)v.y, (__bf16)v.z, (__bf16)v.w};
  dst[off] = o;
}

// ---------------------------------------------------------------------------
// gemm_bt: 8-phase 256x256xBK64 (T3+T4+T5) with R7 swizzle fix. Grid 8x32 =
// 256 blocks = exactly 1/CU (no dispatch-round tail). ~120us by subtraction
// (R8), better than the ~140us 2-phase version -> kept.
// ---------------------------------------------------------------------------
#define STAGE2(gsrc, ldst, KK)                                  \
  do {                                                          \
    gload16((gsrc), (ldst) + tid * 8);                          \
    gload16((gsrc) + (size_t)128 * (KK), (ldst) + 4096 + tid * 8); \
  } while (0)

__global__ __launch_bounds__(512, 2) void gemm_bt(const bf16_t* __restrict__ A,
                                                  const bf16_t* __restrict__ B,
                                                  void* __restrict__ Cp,
                                                  int M, int N, int K, int out_bf16) {
  __shared__ __align__(16) bf16_t Ab[2 * 16384];  // [buf][kk][256][32]
  __shared__ __align__(16) bf16_t Bb[2 * 16384];
  const int tid = threadIdx.x;
  const int w = tid >> 6, lane = tid & 63;
  const int m16 = lane & 15, q4 = lane >> 4;
  const int wr = w >> 2, wc = w & 3;
  const int rowBase = blockIdx.y * 256, colBase = blockIdx.x * 256;

  const int srow = tid >> 2, skc = tid & 3;
  const int sswz = (skc ^ (srow & 3) ^ ((srow >> 2) & 3)) & 3;
  const bf16_t* srcA = A + (size_t)(rowBase + srow) * K + sswz * 8;
  const bf16_t* srcB = B + (size_t)(colBase + srow) * K + sswz * 8;

  const int cs = (q4 ^ (m16 & 3) ^ ((m16 >> 2) & 3)) & 3;
  const int aoff = wr * 4096 + m16 * 32 + cs * 8;
  const int boff = wc * 2048 + m16 * 32 + cs * 8;

  f32x4 acc[8][4];
#pragma unroll
  for (int i = 0; i < 8; ++i)
#pragma unroll
    for (int j = 0; j < 4; ++j) acc[i][j] = (f32x4){0.f, 0.f, 0.f, 0.f};

  const int nt = K >> 6;
  STAGE2(srcA, Ab, K);
  STAGE2(srcB, Bb, K);
  STAGE2(srcA + 32, Ab + 8192, K);
  STAGE2(srcB + 32, Bb + 8192, K);
  asm volatile("s_waitcnt vmcnt(4)" ::: "memory");
  __builtin_amdgcn_s_barrier();

#pragma unroll 1
  for (int t = 0; t < nt; ++t) {
    const int cb = (t & 1) << 14, nb = cb ^ 16384;
    const int pk = ((t + 1 < nt) ? t + 1 : t) << 6;
    const bf16_t* Ac = Ab + cb + aoff;
    const bf16_t* Bc = Bb + cb + boff;
    bf16x8 a[4], b[4];

    STAGE2(srcA + pk, Ab + nb, K);
#pragma unroll
    for (int i = 0; i < 4; ++i) a[i] = *(const bf16x8*)(Ac + i * 512);
#pragma unroll
    for (int j = 0; j < 4; ++j) b[j] = *(const bf16x8*)(Bc + j * 512);
    __builtin_amdgcn_s_barrier();
    asm volatile("s_waitcnt lgkmcnt(0)" ::: "memory");
    __builtin_amdgcn_sched_barrier(0);
    __builtin_amdgcn_s_setprio(1);
#pragma unroll
    for (int i = 0; i < 4; ++i)
#pragma unroll
      for (int j = 0; j < 4; ++j)
        acc[i][j] = __builtin_amdgcn_mfma_f32_16x16x32_bf16(a[i], b[j], acc[i][j], 0, 0, 0);
    __builtin_amdgcn_s_setprio(0);
    __builtin_amdgcn_s_barrier();

    STAGE2(srcB + pk, Bb + nb, K);
#pragma unroll
    for (int i = 0; i < 4; ++i) a[i] = *(const bf16x8*)(Ac + (4 + i) * 512);
    __builtin_amdgcn_s_barrier();
    asm volatile("s_waitcnt lgkmcnt(0)" ::: "memory");
    __builtin_amdgcn_sched_barrier(0);
    __builtin_amdgcn_s_setprio(1);
#pragma unroll
    for (int i = 0; i < 4; ++i)
#pragma unroll
      for (int j = 0; j < 4; ++j)
        acc[4 + i][j] = __builtin_amdgcn_mfma_f32_16x16x32_bf16(a[i], b[j], acc[4 + i][j], 0, 0, 0);
    __builtin_amdgcn_s_setprio(0);
    asm volatile("s_waitcnt vmcnt(4)" ::: "memory");
    __builtin_amdgcn_s_barrier();

    STAGE2(srcA + pk + 32, Ab + nb + 8192, K);
#pragma unroll
    for (int i = 0; i < 4; ++i) a[i] = *(const bf16x8*)(Ac + 8192 + i * 512);
#pragma unroll
    for (int j = 0; j < 4; ++j) b[j] = *(const bf16x8*)(Bc + 8192 + j * 512);
    __builtin_amdgcn_s_barrier();
    asm volatile("s_waitcnt lgkmcnt(0)" ::: "memory");
    __builtin_amdgcn_sched_barrier(0);
    __builtin_amdgcn_s_setprio(1);
#pragma unroll
    for (int i = 0; i < 4; ++i)
#pragma unroll
      for (int j = 0; j < 4; ++j)
        acc[i][j] = __builtin_amdgcn_mfma_f32_16x16x32_bf16(a[i], b[j], acc[i][j], 0, 0, 0);
    __builtin_amdgcn_s_setprio(0);
    __builtin_amdgcn_s_barrier();

    STAGE2(srcB + pk + 32, Bb + nb + 8192, K);
#pragma unroll
    for (int i = 0; i < 4; ++i) a[i] = *(const bf16x8*)(Ac + 8192 + (4 + i) * 512);
    __builtin_amdgcn_s_barrier();
    asm volatile("s_waitcnt lgkmcnt(0)" ::: "memory");
    __builtin_amdgcn_sched_barrier(0);
    __builtin_amdgcn_s_setprio(1);
#pragma unroll
    for (int i = 0; i < 4; ++i)
#pragma unroll
      for (int j = 0; j < 4; ++j)
        acc[4 + i][j] = __builtin_amdgcn_mfma_f32_16x16x32_bf16(a[i], b[j], acc[4 + i][j], 0, 0, 0);
    __builtin_amdgcn_s_setprio(0);
    asm volatile("s_waitcnt vmcnt(4)" ::: "memory");
    __builtin_amdgcn_s_barrier();
  }

  if (out_bf16) {
    bf16_t* C = (bf16_t*)Cp;
#pragma unroll
    for (int i = 0; i < 8; ++i)
#pragma unroll
      for (int j = 0; j < 4; ++j)
#pragma unroll
        for (int r = 0; r < 4; ++r) {
          int row = rowBase + wr * 128 + i * 16 + q4 * 4 + r;
          int col = colBase + wc * 64 + j * 16 + m16;
          C[(size_t)row * N + col] = (bf16_t)acc[i][j][r];
        }
  } else {
    float* C = (float*)Cp;
#pragma unroll
    for (int i = 0; i < 8; ++i)
#pragma unroll
      for (int j = 0; j < 4; ++j)
#pragma unroll
        for (int r = 0; r < 4; ++r) {
          int row = rowBase + wr * 128 + i * 16 + q4 * 4 + r;
          int col = colBase + wc * 64 + j * 16 + m16;
          C[(size_t)row * N + col] = acc[i][j][r];
        }
  }
}

// ---------------------------------------------------------------------------
// QKV GEMM with fused epilogue: M=8192, N=3072, K=2048. REVERTED to R10
// exact (best measured: 170us, MfmaUtil 26): BK=64 + split intra-tile wait:
//   stage 8 -> vmcnt(4)+bar (half0 landed) -> compute h0
//   -> vmcnt(0)+bar -> compute h1 -> syncthreads (no-op drain).
// R11's rotated 4-barrier/tile pipeline REGRESSED (170->180): barrier count
// dominates at 4 blocks/CU -- fewer, fatter sync points win in 2-phase.
// Col-tile bx: 0..15 = q heads, 16..19 = k heads, 20..23 = v heads.
// ---------------------------------------------------------------------------
__global__ __launch_bounds__(256) void gemm_qkv(const bf16_t* __restrict__ A,
                                                const bf16_t* __restrict__ Bw,
                                                bf16_t* __restrict__ qkv,
                                                bf16_t* __restrict__ vt,
                                                const float* __restrict__ gain) {
  __shared__ bf16_t As[2 * 128 * 32];  // [half][row][32K]
  __shared__ bf16_t Bs[2 * 128 * 32];
  __shared__ float ssbuf[2][128];
  const int tid = threadIdx.x;
  const int w = tid >> 6, lane = tid & 63;
  const int m = lane & 15, quad = lane >> 4;
  const int wr = w >> 1, wc = w & 1;
  const int rowBase = blockIdx.y * 128, colBase = blockIdx.x * 128;

  f32x4 acc[4][4];
#pragma unroll
  for (int i = 0; i < 4; ++i)
#pragma unroll
    for (int j = 0; j < 4; ++j) acc[i][j] = (f32x4){0.f, 0.f, 0.f, 0.f};

  for (int t = 0; t < 32; ++t) {
    const int k0 = t << 6;
    // stage BK=64, half0 chunks first: idx = half*512 + row*4 + kc
#pragma unroll
    for (int i2 = 0; i2 < 4; ++i2) {
      int idx = i2 * 256 + tid;
      int half = idx >> 9, row = (idx >> 2) & 127, kc = idx & 3;
      int gk = k0 + half * 32 + kc * 8;
      gload16(A + (size_t)(rowBase + row) * 2048 + gk, &As[idx * 8]);
      gload16(Bw + (size_t)(colBase + row) * 2048 + gk, &Bs[idx * 8]);
    }
    asm volatile("s_waitcnt vmcnt(4)" ::: "memory");  // half0 landed
    __builtin_amdgcn_s_barrier();
    {
      bf16x8 a[4], bb[4];
#pragma unroll
      for (int i = 0; i < 4; ++i)
        a[i] = *(const bf16x8*)&As[(wr * 64 + i * 16 + m) * 32 + quad * 8];
#pragma unroll
      for (int j = 0; j < 4; ++j)
        bb[j] = *(const bf16x8*)&Bs[(wc * 64 + j * 16 + m) * 32 + quad * 8];
#pragma unroll
      for (int i = 0; i < 4; ++i)
#pragma unroll
        for (int j = 0; j < 4; ++j)
          acc[i][j] = __builtin_amdgcn_mfma_f32_16x16x32_bf16(a[i], bb[j], acc[i][j], 0, 0, 0);
    }
    asm volatile("s_waitcnt vmcnt(0)" ::: "memory");  // half1 landed
    __builtin_amdgcn_s_barrier();
    {
      const bf16_t* Ah = As + 4096;
      const bf16_t* Bh = Bs + 4096;
      bf16x8 a[4], bb[4];
#pragma unroll
      for (int i = 0; i < 4; ++i)
        a[i] = *(const bf16x8*)&Ah[(wr * 64 + i * 16 + m) * 32 + quad * 8];
#pragma unroll
      for (int j = 0; j < 4; ++j)
        bb[j] = *(const bf16x8*)&Bh[(wc * 64 + j * 16 + m) * 32 + quad * 8];
#pragma unroll
      for (int i = 0; i < 4; ++i)
#pragma unroll
        for (int j = 0; j < 4; ++j)
          acc[i][j] = __builtin_amdgcn_mfma_f32_16x16x32_bf16(a[i], bb[j], acc[i][j], 0, 0, 0);
    }
    __syncthreads();  // protect LDS before next tile's staging (drain no-op)
  }

  const int bx = blockIdx.x;
  if (bx < 20) {
    // ---- q/k epilogue: RMSNorm + RoPE
    const float g = (bx < 16) ? gain[bx] * QSCALE : 1.0f;
#pragma unroll
    for (int i = 0; i < 4; ++i) {
      float ssp[4];
#pragma unroll
      for (int r = 0; r < 4; ++r) {
        float s = 0.f;
#pragma unroll
        for (int j = 0; j < 4; ++j) s += acc[i][j][r] * acc[i][j][r];
#pragma unroll
        for (int off = 1; off <= 8; off <<= 1) s += __shfl_xor(s, off);
        ssp[r] = s;
      }
      if (m == 0) {
#pragma unroll
        for (int r = 0; r < 4; ++r) ssbuf[wc][wr * 64 + i * 16 + quad * 4 + r] = ssp[r];
      }
    }
    __syncthreads();
    const float if0 = exp2f(-(float)m * 0.4152410118609203f);
    const float if1 = exp2f(-(float)(16 + m) * 0.4152410118609203f);
#pragma unroll
    for (int i = 0; i < 4; ++i) {
#pragma unroll
      for (int r = 0; r < 4; ++r) {
        const int ridx = wr * 64 + i * 16 + quad * 4 + r;
        const int row = rowBase + ridx;
        const float rn = rsqrtf((ssbuf[0][ridx] + ssbuf[1][ridx]) * (1.f / 128.f) + 1e-6f);
        float v0 = acc[i][0][r] * rn, v1 = acc[i][1][r] * rn;
        float v2 = acc[i][2][r] * rn, v3 = acc[i][3][r] * rn;
        float o0 = v0, o1 = v1, o2 = v2, o3 = v3;
        if (wc == 0) {  // cols 0..63 of head: rotate pairs (d, d+32)
          const float t2 = (float)(row & (T_ - 1));
          const float a0 = t2 * if0, a1 = t2 * if1;
          const float c0_ = cosf(a0), s0_ = sinf(a0);
          const float c1_ = cosf(a1), s1_ = sinf(a1);
          o0 = v0 * c0_ - v2 * s0_;
          o1 = v1 * c1_ - v3 * s1_;
          o2 = v2 * c0_ + v0 * s0_;
          o3 = v3 * c1_ + v1 * s1_;
        }
        bf16_t* out = qkv + (size_t)row * QKV_ + colBase + wc * 64 + m;
        out[0]  = (bf16_t)(o0 * g);
        out[16] = (bf16_t)(o1 * g);
        out[32] = (bf16_t)(o2 * g);
        out[48] = (bf16_t)(o3 * g);
      }
    }
  } else {
    // ---- v epilogue: raw row-major store + transposed store into vt
    const int kvh = bx - 20;
#pragma unroll
    for (int i = 0; i < 4; ++i)
#pragma unroll
      for (int j = 0; j < 4; ++j) {
        const int row0 = rowBase + wr * 64 + i * 16 + quad * 4;
        const int d = wc * 64 + j * 16 + m;
        bf16x4 pv;
#pragma unroll
        for (int r = 0; r < 4; ++r) {
          pv[r] = (bf16_t)acc[i][j][r];
          qkv[(size_t)(row0 + r) * QKV_ + colBase + d] = pv[r];
        }
        const int b = row0 >> 11, t0 = row0 & (T_ - 1);
        *(bf16x4*)(vt + ((size_t)(b * KVH_ + kvh) * HD_ + d) * T_ + t0) = pv;
      }
  }
}

// ---------------------------------------------------------------------------
// Flash attention, S^T formulation, software-pipelined. R12: SINGLE q-tile
// per block, grid (16,16,4) = 1024 blocks, longest-first (qb=(15-bx)*128).
// Isolates the grid change R1 confounded with T13 (R1 grid+T13 = 283us,
// R2 paired+T13 = 282us -> T13 alone explained the regression; grid alone
// never measured). LDS 43KB -> 3 blocks/CU co-resident (vs 2 with paired
// 512 blocks) = 3-way stall overlap; x-major dispatch launches all 64
// longest blocks (bx=0, 64 iters) in the first wave.
// NO-MAX softmax (scores bounded), deferred l-reduction. 4 waves x 32
// q-rows. K-step 32, double-buffered K/V LDS via global_load_lds.
// ---------------------------------------------------------------------------
__global__ __launch_bounds__(256) void attn_kernel(const bf16_t* __restrict__ qkv,
                                                   const bf16_t* __restrict__ vt,
                                                   bf16_t* __restrict__ y) {
  __shared__ __align__(16) bf16_t Ks[2][32 * 128];
  __shared__ __align__(16) bf16_t Vs[2][128 * 32];
  __shared__ __align__(16) bf16_t Ps[4][32 * 40];

  const int tid = threadIdx.x;
  const int w = tid >> 6, lane = tid & 63;
  const int m = lane & 15, q = lane >> 4;
  const int h = blockIdx.y, b = blockIdx.z, kvh = h >> 2;

  const bf16_t* qptr = qkv + (size_t)(b * T_) * QKV_ + h * HD_;
  const bf16_t* kptr = qkv + (size_t)(b * T_) * QKV_ + DIM_ + kvh * HD_;
  const bf16_t* vptr = qkv + (size_t)(b * T_) * QKV_ + DIM_ + KVH_ * HD_ + kvh * HD_;
  const bf16_t* vtptr = vt + (size_t)(b * KVH_ + kvh) * HD_ * T_;

  const int kKey0 = tid >> 4, kC0 = tid & 15;
  const int kKey1 = (256 + tid) >> 4, kC1 = tid & 15;
  const int vD0 = tid >> 2, vC0 = tid & 3;
  const int vD1 = (256 + tid) >> 2, vC1 = tid & 3;
  const int vS0 = (vD0 ^ (vD0 >> 2)) & 3, vS1 = (vD1 ^ (vD1 >> 2)) & 3;

  int koff[2][4], voff[8], poff[2];
#pragma unroll
  for (int kf = 0; kf < 2; ++kf)
#pragma unroll
    for (int c = 0; c < 4; ++c)
      koff[kf][c] = (kf * 16 + m) * 128 + (((c * 4 + q) ^ m) & 15) * 8;
#pragma unroll
  for (int f = 0; f < 8; ++f) {
    const int d = f * 16 + m;
    voff[f] = d * 32 + ((q ^ ((d ^ (d >> 2)) & 3)) & 3) * 8;
  }
#pragma unroll
  for (int qf = 0; qf < 2; ++qf) poff[qf] = (qf * 16 + m) * 40 + q * 8;

  const int qb = (15 - (int)blockIdx.x) * 128;  // longest tiles first
  const int qbw = qb + w * 32;
  const int nk = (qb >> 5) + 4;

  bf16x8 aq[2][4];
#pragma unroll
  for (int qf = 0; qf < 2; ++qf)
#pragma unroll
    for (int c = 0; c < 4; ++c)
      aq[qf][c] = *(const bf16x8*)(qptr + (size_t)(qbw + qf * 16 + m) * QKV_ + c * 32 + q * 8);

  f32x4 o[2][8];
#pragma unroll
  for (int qf = 0; qf < 2; ++qf)
#pragma unroll
    for (int f = 0; f < 8; ++f) o[qf][f] = (f32x4){0.f, 0.f, 0.f, 0.f};
  float l_r[2] = {0.f, 0.f};  // lane-local partial; reduced in epilogue

  {
    gload16(kptr + (size_t)kKey0 * QKV_ + ((kC0 ^ kKey0) & 15) * 8, &Ks[0][tid * 8]);
    gload16(kptr + (size_t)kKey1 * QKV_ + ((kC1 ^ kKey1) & 15) * 8, &Ks[0][(256 + tid) * 8]);
    gload16(vtptr + (size_t)vD0 * T_ + (vC0 ^ vS0) * 8, &Vs[0][tid * 8]);
    gload16(vtptr + (size_t)vD1 * T_ + (vC1 ^ vS1) * 8, &Vs[0][(256 + tid) * 8]);
  }

#pragma unroll 1
  for (int it = 0; it < nk; ++it) {
    const int kb = it << 5;
    __syncthreads();

    if (it + 1 < nk) {
      const int kb2 = kb + 32;
      bf16_t* Kb = Ks[(it + 1) & 1];
      bf16_t* Vb = Vs[(it + 1) & 1];
      gload16(kptr + (size_t)(kb2 + kKey0) * QKV_ + ((kC0 ^ kKey0) & 15) * 8, &Kb[tid * 8]);
      gload16(kptr + (size_t)(kb2 + kKey1) * QKV_ + ((kC1 ^ kKey1) & 15) * 8, &Kb[(256 + tid) * 8]);
      gload16(vtptr + (size_t)vD0 * T_ + kb2 + (vC0 ^ vS0) * 8, &Vb[tid * 8]);
      gload16(vtptr + (size_t)vD1 * T_ + kb2 + (vC1 ^ vS1) * 8, &Vb[(256 + tid) * 8]);
    }

    if (kb > qbw + 31) continue;
    const bf16_t* Kb = Ks[it & 1];
    const bf16_t* Vb = Vs[it & 1];

    f32x4 S[2][2];
#pragma unroll
    for (int qf = 0; qf < 2; ++qf)
#pragma unroll
      for (int kf = 0; kf < 2; ++kf) S[qf][kf] = (f32x4){0.f, 0.f, 0.f, 0.f};
#pragma unroll
    for (int kf = 0; kf < 2; ++kf)
#pragma unroll
      for (int c = 0; c < 4; ++c) {
        bf16x8 ak = *(const bf16x8*)&Kb[koff[kf][c]];
        S[0][kf] = __builtin_amdgcn_mfma_f32_16x16x32_bf16(ak, aq[0][c], S[0][kf], 0, 0, 0);
        S[1][kf] = __builtin_amdgcn_mfma_f32_16x16x32_bf16(ak, aq[1][c], S[1][kf], 0, 0, 0);
      }

    const bool needmask = (kb + 31) > qbw;
#pragma unroll
    for (int qf = 0; qf < 2; ++qf) {
      const int qrow = qbw + qf * 16 + m;
      if (needmask) {
#pragma unroll
        for (int kf = 0; kf < 2; ++kf)
#pragma unroll
          for (int r = 0; r < 4; ++r) {
            int key = kb + kf * 16 + q * 4 + r;
            if (key > qrow) S[qf][kf][r] = -1e30f;
          }
      }
      float rs = 0.f;
#pragma unroll
      for (int kf = 0; kf < 2; ++kf)
#pragma unroll
        for (int r = 0; r < 4; ++r) {
          float p = exp2f(S[qf][kf][r]);
          S[qf][kf][r] = p;
          rs += p;
        }
      l_r[qf] += rs;  // lane-local; cross-lane reduce deferred to epilogue
#pragma unroll
      for (int kf = 0; kf < 2; ++kf) {
        bf16x4 pk = {(__bf16)S[qf][kf][0], (__bf16)S[qf][kf][1],
                     (__bf16)S[qf][kf][2], (__bf16)S[qf][kf][3]};
        *(bf16x4*)&Ps[w][(qf * 16 + m) * 40 + kf * 16 + q * 4] = pk;
      }
    }
    asm volatile("s_waitcnt lgkmcnt(0)" ::: "memory");

    bf16x8 Pb[2];
#pragma unroll
    for (int qf = 0; qf < 2; ++qf)
      Pb[qf] = *(const bf16x8*)&Ps[w][poff[qf]];
#pragma unroll
    for (int f = 0; f < 8; ++f) {
      bf16x8 av = *(const bf16x8*)&Vb[voff[f]];
      o[0][f] = __builtin_amdgcn_mfma_f32_16x16x32_bf16(av, Pb[0], o[0][f], 0, 0, 0);
      o[1][f] = __builtin_amdgcn_mfma_f32_16x16x32_bf16(av, Pb[1], o[1][f], 0, 0, 0);
    }
  }

#pragma unroll
  for (int qf = 0; qf < 2; ++qf) {
    const int trow = qbw + qf * 16 + m;
    float lt = l_r[qf];
    lt += __shfl_xor(lt, 16);
    lt += __shfl_xor(lt, 32);
    const float linv = 1.f / lt;
    bf16x4 vv[8];
    float n2 = 0.f, dp = 0.f;
#pragma unroll
    for (int f = 0; f < 8; ++f) {
      vv[f] = *(const bf16x4*)(vptr + (size_t)trow * QKV_ + f * 16 + q * 4);
#pragma unroll
      for (int r = 0; r < 4; ++r) {
        float v = (float)vv[f][r];
        n2 += v * v;
        dp += o[qf][f][r] * linv * v;
      }
    }
    n2 += __shfl_xor(n2, 16); n2 += __shfl_xor(n2, 32);
    dp += __shfl_xor(dp, 16); dp += __shfl_xor(dp, 32);
    float d = fmaxf(sqrtf(n2), 1e-12f);
    float coef = dp / (d * d);
#pragma unroll
    for (int f = 0; f < 8; ++f) {
      bf16x4 yo;
#pragma unroll
      for (int r = 0; r < 4; ++r)
        yo[r] = (bf16_t)(o[qf][f][r] * linv - coef * (float)vv[f][r]);
      *(bf16x4*)(y + (size_t)(b * T_ + trow) * DIM_ + h * HD_ + f * 16 + q * 4) = yo;
    }
  }
}

// ---------------------------------------------------------------------------
extern "C" void kernel_launch(void* const* d_in, const int* in_sizes, int n_in,
                              void* d_out, int out_size, void* d_ws, size_t ws_size,
                              hipStream_t stream) {
  const float* x = (const float*)d_in[0];
  const float* Wq = (const float*)d_in[1];
  const float* Wk = (const float*)d_in[2];
  const float* Wv = (const float*)d_in[3];
  const float* Wp = (const float*)d_in[4];
  const float* qg = (const float*)d_in[5];

  bf16_t* xbf = (bf16_t*)d_ws;                        // 8192*2048
  bf16_t* wqkv = xbf + (size_t)8192 * 2048;           // 3072*2048
  bf16_t* wproj = wqkv + (size_t)3072 * 2048;         // 2048*2048
  bf16_t* qkv = wproj + (size_t)2048 * 2048;          // 8192*3072
  bf16_t* vt = qkv + (size_t)8192 * 3072;             // 16*128*2048
  bf16_t* ybf = xbf;                                  // reuse after gemm_qkv

  cvt_all<<<26624, 256, 0, stream>>>((const float4*)x, (const float4*)Wq,
                                     (const float4*)Wk, (const float4*)Wv,
                                     (const float4*)Wp, (bf16x4*)xbf,
                                     (bf16x4*)wqkv, (bf16x4*)wproj);
  gemm_qkv<<<dim3(24, 64), 256, 0, stream>>>(xbf, wqkv, qkv, vt, qg);
  attn_kernel<<<dim3(16, 16, 4), 256, 0, stream>>>(qkv, vt, ybf);
  gemm_bt<<<dim3(8, 32), 512, 0, stream>>>(ybf, wproj, d_out, 8192, 2048, 2048, 0);
}

// Round 13
// 497.110 us; speedup vs baseline: 1.2465x; 1.2465x over previous
//
#include <hip/hip_runtime.h>
#include <cstdint>
#include <cstddef>

typedef __bf16 bf16_t;
typedef __bf16 bf16x4 __attribute__((ext_vector_type(4)));
typedef __bf16 bf16x8 __attribute__((ext_vector_type(8)));
typedef float f32x4 __attribute__((ext_vector_type(4)));

#define B_ 4
#define T_ 2048
#define DIM_ 2048
#define H_ 16
#define KVH_ 4
#define HD_ 128
#define QKV_ 3072
// SCALE * log2(e): folded into q rows in the gemm_qkv epilogue; attn uses exp2.
#define QSCALE (0.08838834764831845f * 1.4426950408889634f)

// ---------------------------------------------------------------------------
// async global->LDS, 16B per lane. LDS dest = wave-uniform base + lane*16B.
// Dest pointer arithmetic is in ELEMENTS: 8 bf16 = 16B per lane.
// ---------------------------------------------------------------------------
__device__ __forceinline__ void gload16(const bf16_t* g, bf16_t* l) {
  __builtin_amdgcn_global_load_lds(
      (const __attribute__((address_space(1))) unsigned int*)g,
      (__attribute__((address_space(3))) unsigned int*)l, 16, 0, 0);
}

// ---------------------------------------------------------------------------
// fused fp32 -> bf16 convert for all five inputs (one launch).
// ---------------------------------------------------------------------------
__global__ __launch_bounds__(256) void cvt_all(const float4* __restrict__ x,
                                               const float4* __restrict__ wq,
                                               const float4* __restrict__ wk,
                                               const float4* __restrict__ wv,
                                               const float4* __restrict__ wp,
                                               bf16x4* __restrict__ xb,
                                               bf16x4* __restrict__ wqkvb,
                                               bf16x4* __restrict__ wpb) {
  int i = blockIdx.x * 256 + threadIdx.x;
  const float4* s;
  bf16x4* dst;
  int off;
  if (i < 4194304) { s = x; dst = xb; off = i; }
  else if (i < 5242880) { s = wq; dst = wqkvb; off = i - 4194304; }
  else if (i < 5505024) { s = wk; dst = wqkvb + 1048576; off = i - 5242880; }
  else if (i < 5767168) { s = wv; dst = wqkvb + 1310720; off = i - 5505024; }
  else { s = wp; dst = wpb; off = i - 5767168; }
  float4 v = s[off];
  bf16x4 o = {(__bf16)v.x, (__bf16)v.y, (__bf16)v.z, (__bf16)v.w};
  dst[off] = o;
}

// ---------------------------------------------------------------------------
// gemm_bt: 8-phase 256x256xBK64 (T3+T4+T5) with R7 swizzle fix. Grid 8x32 =
// 256 blocks = exactly 1/CU (no dispatch-round tail). ~120us by subtraction
// (R8), better than the ~140us 2-phase version -> kept.
// ---------------------------------------------------------------------------
#define STAGE2(gsrc, ldst, KK)                                  \
  do {                                                          \
    gload16((gsrc), (ldst) + tid * 8);                          \
    gload16((gsrc) + (size_t)128 * (KK), (ldst) + 4096 + tid * 8); \
  } while (0)

__global__ __launch_bounds__(512, 2) void gemm_bt(const bf16_t* __restrict__ A,
                                                  const bf16_t* __restrict__ B,
                                                  void* __restrict__ Cp,
                                                  int M, int N, int K, int out_bf16) {
  __shared__ __align__(16) bf16_t Ab[2 * 16384];  // [buf][kk][256][32]
  __shared__ __align__(16) bf16_t Bb[2 * 16384];
  const int tid = threadIdx.x;
  const int w = tid >> 6, lane = tid & 63;
  const int m16 = lane & 15, q4 = lane >> 4;
  const int wr = w >> 2, wc = w & 3;
  const int rowBase = blockIdx.y * 256, colBase = blockIdx.x * 256;

  const int srow = tid >> 2, skc = tid & 3;
  const int sswz = (skc ^ (srow & 3) ^ ((srow >> 2) & 3)) & 3;
  const bf16_t* srcA = A + (size_t)(rowBase + srow) * K + sswz * 8;
  const bf16_t* srcB = B + (size_t)(colBase + srow) * K + sswz * 8;

  const int cs = (q4 ^ (m16 & 3) ^ ((m16 >> 2) & 3)) & 3;
  const int aoff = wr * 4096 + m16 * 32 + cs * 8;
  const int boff = wc * 2048 + m16 * 32 + cs * 8;

  f32x4 acc[8][4];
#pragma unroll
  for (int i = 0; i < 8; ++i)
#pragma unroll
    for (int j = 0; j < 4; ++j) acc[i][j] = (f32x4){0.f, 0.f, 0.f, 0.f};

  const int nt = K >> 6;
  STAGE2(srcA, Ab, K);
  STAGE2(srcB, Bb, K);
  STAGE2(srcA + 32, Ab + 8192, K);
  STAGE2(srcB + 32, Bb + 8192, K);
  asm volatile("s_waitcnt vmcnt(4)" ::: "memory");
  __builtin_amdgcn_s_barrier();

#pragma unroll 1
  for (int t = 0; t < nt; ++t) {
    const int cb = (t & 1) << 14, nb = cb ^ 16384;
    const int pk = ((t + 1 < nt) ? t + 1 : t) << 6;
    const bf16_t* Ac = Ab + cb + aoff;
    const bf16_t* Bc = Bb + cb + boff;
    bf16x8 a[4], b[4];

    STAGE2(srcA + pk, Ab + nb, K);
#pragma unroll
    for (int i = 0; i < 4; ++i) a[i] = *(const bf16x8*)(Ac + i * 512);
#pragma unroll
    for (int j = 0; j < 4; ++j) b[j] = *(const bf16x8*)(Bc + j * 512);
    __builtin_amdgcn_s_barrier();
    asm volatile("s_waitcnt lgkmcnt(0)" ::: "memory");
    __builtin_amdgcn_sched_barrier(0);
    __builtin_amdgcn_s_setprio(1);
#pragma unroll
    for (int i = 0; i < 4; ++i)
#pragma unroll
      for (int j = 0; j < 4; ++j)
        acc[i][j] = __builtin_amdgcn_mfma_f32_16x16x32_bf16(a[i], b[j], acc[i][j], 0, 0, 0);
    __builtin_amdgcn_s_setprio(0);
    __builtin_amdgcn_s_barrier();

    STAGE2(srcB + pk, Bb + nb, K);
#pragma unroll
    for (int i = 0; i < 4; ++i) a[i] = *(const bf16x8*)(Ac + (4 + i) * 512);
    __builtin_amdgcn_s_barrier();
    asm volatile("s_waitcnt lgkmcnt(0)" ::: "memory");
    __builtin_amdgcn_sched_barrier(0);
    __builtin_amdgcn_s_setprio(1);
#pragma unroll
    for (int i = 0; i < 4; ++i)
#pragma unroll
      for (int j = 0; j < 4; ++j)
        acc[4 + i][j] = __builtin_amdgcn_mfma_f32_16x16x32_bf16(a[i], b[j], acc[4 + i][j], 0, 0, 0);
    __builtin_amdgcn_s_setprio(0);
    asm volatile("s_waitcnt vmcnt(4)" ::: "memory");
    __builtin_amdgcn_s_barrier();

    STAGE2(srcA + pk + 32, Ab + nb + 8192, K);
#pragma unroll
    for (int i = 0; i < 4; ++i) a[i] = *(const bf16x8*)(Ac + 8192 + i * 512);
#pragma unroll
    for (int j = 0; j < 4; ++j) b[j] = *(const bf16x8*)(Bc + 8192 + j * 512);
    __builtin_amdgcn_s_barrier();
    asm volatile("s_waitcnt lgkmcnt(0)" ::: "memory");
    __builtin_amdgcn_sched_barrier(0);
    __builtin_amdgcn_s_setprio(1);
#pragma unroll
    for (int i = 0; i < 4; ++i)
#pragma unroll
      for (int j = 0; j < 4; ++j)
        acc[i][j] = __builtin_amdgcn_mfma_f32_16x16x32_bf16(a[i], b[j], acc[i][j], 0, 0, 0);
    __builtin_amdgcn_s_setprio(0);
    __builtin_amdgcn_s_barrier();

    STAGE2(srcB + pk + 32, Bb + nb + 8192, K);
#pragma unroll
    for (int i = 0; i < 4; ++i) a[i] = *(const bf16x8*)(Ac + 8192 + (4 + i) * 512);
    __builtin_amdgcn_s_barrier();
    asm volatile("s_waitcnt lgkmcnt(0)" ::: "memory");
    __builtin_amdgcn_sched_barrier(0);
    __builtin_amdgcn_s_setprio(1);
#pragma unroll
    for (int i = 0; i < 4; ++i)
#pragma unroll
      for (int j = 0; j < 4; ++j)
        acc[4 + i][j] = __builtin_amdgcn_mfma_f32_16x16x32_bf16(a[i], b[j], acc[4 + i][j], 0, 0, 0);
    __builtin_amdgcn_s_setprio(0);
    asm volatile("s_waitcnt vmcnt(4)" ::: "memory");
    __builtin_amdgcn_s_barrier();
  }

  if (out_bf16) {
    bf16_t* C = (bf16_t*)Cp;
#pragma unroll
    for (int i = 0; i < 8; ++i)
#pragma unroll
      for (int j = 0; j < 4; ++j)
#pragma unroll
        for (int r = 0; r < 4; ++r) {
          int row = rowBase + wr * 128 + i * 16 + q4 * 4 + r;
          int col = colBase + wc * 64 + j * 16 + m16;
          C[(size_t)row * N + col] = (bf16_t)acc[i][j][r];
        }
  } else {
    float* C = (float*)Cp;
#pragma unroll
    for (int i = 0; i < 8; ++i)
#pragma unroll
      for (int j = 0; j < 4; ++j)
#pragma unroll
        for (int r = 0; r < 4; ++r) {
          int row = rowBase + wr * 128 + i * 16 + q4 * 4 + r;
          int col = colBase + wc * 64 + j * 16 + m16;
          C[(size_t)row * N + col] = acc[i][j][r];
        }
  }
}

// ---------------------------------------------------------------------------
// QKV GEMM with fused epilogue: M=8192, N=3072, K=2048. R10-exact (best
// measured: 170us): BK=64 + split intra-tile wait.
// Col-tile bx: 0..15 = q heads, 16..19 = k heads, 20..23 = v heads.
// ---------------------------------------------------------------------------
__global__ __launch_bounds__(256) void gemm_qkv(const bf16_t* __restrict__ A,
                                                const bf16_t* __restrict__ Bw,
                                                bf16_t* __restrict__ qkv,
                                                bf16_t* __restrict__ vt,
                                                const float* __restrict__ gain) {
  __shared__ bf16_t As[2 * 128 * 32];  // [half][row][32K]
  __shared__ bf16_t Bs[2 * 128 * 32];
  __shared__ float ssbuf[2][128];
  const int tid = threadIdx.x;
  const int w = tid >> 6, lane = tid & 63;
  const int m = lane & 15, quad = lane >> 4;
  const int wr = w >> 1, wc = w & 1;
  const int rowBase = blockIdx.y * 128, colBase = blockIdx.x * 128;

  f32x4 acc[4][4];
#pragma unroll
  for (int i = 0; i < 4; ++i)
#pragma unroll
    for (int j = 0; j < 4; ++j) acc[i][j] = (f32x4){0.f, 0.f, 0.f, 0.f};

  for (int t = 0; t < 32; ++t) {
    const int k0 = t << 6;
#pragma unroll
    for (int i2 = 0; i2 < 4; ++i2) {
      int idx = i2 * 256 + tid;
      int half = idx >> 9, row = (idx >> 2) & 127, kc = idx & 3;
      int gk = k0 + half * 32 + kc * 8;
      gload16(A + (size_t)(rowBase + row) * 2048 + gk, &As[idx * 8]);
      gload16(Bw + (size_t)(colBase + row) * 2048 + gk, &Bs[idx * 8]);
    }
    asm volatile("s_waitcnt vmcnt(4)" ::: "memory");  // half0 landed
    __builtin_amdgcn_s_barrier();
    {
      bf16x8 a[4], bb[4];
#pragma unroll
      for (int i = 0; i < 4; ++i)
        a[i] = *(const bf16x8*)&As[(wr * 64 + i * 16 + m) * 32 + quad * 8];
#pragma unroll
      for (int j = 0; j < 4; ++j)
        bb[j] = *(const bf16x8*)&Bs[(wc * 64 + j * 16 + m) * 32 + quad * 8];
#pragma unroll
      for (int i = 0; i < 4; ++i)
#pragma unroll
        for (int j = 0; j < 4; ++j)
          acc[i][j] = __builtin_amdgcn_mfma_f32_16x16x32_bf16(a[i], bb[j], acc[i][j], 0, 0, 0);
    }
    asm volatile("s_waitcnt vmcnt(0)" ::: "memory");  // half1 landed
    __builtin_amdgcn_s_barrier();
    {
      const bf16_t* Ah = As + 4096;
      const bf16_t* Bh = Bs + 4096;
      bf16x8 a[4], bb[4];
#pragma unroll
      for (int i = 0; i < 4; ++i)
        a[i] = *(const bf16x8*)&Ah[(wr * 64 + i * 16 + m) * 32 + quad * 8];
#pragma unroll
      for (int j = 0; j < 4; ++j)
        bb[j] = *(const bf16x8*)&Bh[(wc * 64 + j * 16 + m) * 32 + quad * 8];
#pragma unroll
      for (int i = 0; i < 4; ++i)
#pragma unroll
        for (int j = 0; j < 4; ++j)
          acc[i][j] = __builtin_amdgcn_mfma_f32_16x16x32_bf16(a[i], bb[j], acc[i][j], 0, 0, 0);
    }
    __syncthreads();  // protect LDS before next tile's staging (drain no-op)
  }

  const int bx = blockIdx.x;
  if (bx < 20) {
    // ---- q/k epilogue: RMSNorm + RoPE
    const float g = (bx < 16) ? gain[bx] * QSCALE : 1.0f;
#pragma unroll
    for (int i = 0; i < 4; ++i) {
      float ssp[4];
#pragma unroll
      for (int r = 0; r < 4; ++r) {
        float s = 0.f;
#pragma unroll
        for (int j = 0; j < 4; ++j) s += acc[i][j][r] * acc[i][j][r];
#pragma unroll
        for (int off = 1; off <= 8; off <<= 1) s += __shfl_xor(s, off);
        ssp[r] = s;
      }
      if (m == 0) {
#pragma unroll
        for (int r = 0; r < 4; ++r) ssbuf[wc][wr * 64 + i * 16 + quad * 4 + r] = ssp[r];
      }
    }
    __syncthreads();
    const float if0 = exp2f(-(float)m * 0.4152410118609203f);
    const float if1 = exp2f(-(float)(16 + m) * 0.4152410118609203f);
#pragma unroll
    for (int i = 0; i < 4; ++i) {
#pragma unroll
      for (int r = 0; r < 4; ++r) {
        const int ridx = wr * 64 + i * 16 + quad * 4 + r;
        const int row = rowBase + ridx;
        const float rn = rsqrtf((ssbuf[0][ridx] + ssbuf[1][ridx]) * (1.f / 128.f) + 1e-6f);
        float v0 = acc[i][0][r] * rn, v1 = acc[i][1][r] * rn;
        float v2 = acc[i][2][r] * rn, v3 = acc[i][3][r] * rn;
        float o0 = v0, o1 = v1, o2 = v2, o3 = v3;
        if (wc == 0) {  // cols 0..63 of head: rotate pairs (d, d+32)
          const float t2 = (float)(row & (T_ - 1));
          const float a0 = t2 * if0, a1 = t2 * if1;
          const float c0_ = cosf(a0), s0_ = sinf(a0);
          const float c1_ = cosf(a1), s1_ = sinf(a1);
          o0 = v0 * c0_ - v2 * s0_;
          o1 = v1 * c1_ - v3 * s1_;
          o2 = v2 * c0_ + v0 * s0_;
          o3 = v3 * c1_ + v1 * s1_;
        }
        bf16_t* out = qkv + (size_t)row * QKV_ + colBase + wc * 64 + m;
        out[0]  = (bf16_t)(o0 * g);
        out[16] = (bf16_t)(o1 * g);
        out[32] = (bf16_t)(o2 * g);
        out[48] = (bf16_t)(o3 * g);
      }
    }
  } else {
    // ---- v epilogue: raw row-major store + transposed store into vt
    const int kvh = bx - 20;
#pragma unroll
    for (int i = 0; i < 4; ++i)
#pragma unroll
      for (int j = 0; j < 4; ++j) {
        const int row0 = rowBase + wr * 64 + i * 16 + quad * 4;
        const int d = wc * 64 + j * 16 + m;
        bf16x4 pv;
#pragma unroll
        for (int r = 0; r < 4; ++r) {
          pv[r] = (bf16_t)acc[i][j][r];
          qkv[(size_t)(row0 + r) * QKV_ + colBase + d] = pv[r];
        }
        const int b = row0 >> 11, t0 = row0 & (T_ - 1);
        *(bf16x4*)(vt + ((size_t)(b * KVH_ + kvh) * HD_ + d) * T_ + t0) = pv;
      }
  }
}

// ---------------------------------------------------------------------------
// Flash attention, S^T formulation. R13: PAIRED grid RESTORED (8,16,4) --
// R12 proved single-tile grid is the regressor (160->257us, occ 12%); load
// balance dominates. NEW: K-tile 64 staged per iteration, computed in two
// 32-key sub-steps (same S/P/PV registers, same accumulation order) ->
// barrier+drain count halves (68->34/block), the R9-validated mechanism.
// LDS: Ks[2][64x128] 32KB + Vs[2][128x64] 32KB + Ps 10KB = 74KB -> 2
// blocks/CU (unchanged; grid 512 = 2/CU). V rows now 8 chunks (128B = one
// bank cycle) -> 8-wide XOR swizzle: slot p of row d holds chunk p^(d&7)
// (bijective); read slot ((s*4+q)^(m&7))&7, uniform in f. K staging formula
// unchanged (key&15 = m for all sub-steps).
// NO-MAX softmax (scores bounded), deferred l-reduction.
// ---------------------------------------------------------------------------
__global__ __launch_bounds__(256) void attn_kernel(const bf16_t* __restrict__ qkv,
                                                   const bf16_t* __restrict__ vt,
                                                   bf16_t* __restrict__ y) {
  __shared__ __align__(16) bf16_t Ks[2][64 * 128];  // [key][hd], slot p of row k holds chunk p^(k&15)
  __shared__ __align__(16) bf16_t Vs[2][128 * 64];  // [d][key], slot p of row d holds chunk p^(d&7)
  __shared__ __align__(16) bf16_t Ps[4][32 * 40];   // per-wave P [qrow][key], stride 40

  const int tid = threadIdx.x;
  const int w = tid >> 6, lane = tid & 63;
  const int m = lane & 15, q = lane >> 4;
  const int h = blockIdx.y, b = blockIdx.z, kvh = h >> 2;

  const bf16_t* qptr = qkv + (size_t)(b * T_) * QKV_ + h * HD_;
  const bf16_t* kptr = qkv + (size_t)(b * T_) * QKV_ + DIM_ + kvh * HD_;
  const bf16_t* vptr = qkv + (size_t)(b * T_) * QKV_ + DIM_ + KVH_ * HD_ + kvh * HD_;
  const bf16_t* vtptr = vt + (size_t)(b * KVH_ + kvh) * HD_ * T_;

  // staging indices (uniform across the 4 rounds of 256 chunks)
  const int kKeyR = tid >> 4;                              // key row in round
  const int kSrcO = (((tid & 15) ^ kKeyR) & 15) * 8;       // pre-swizzled src chunk
  const int vDR = tid >> 3;                                // d row in round
  const int vSrcO = (((tid & 7) ^ (vDR & 7)) & 7) * 8;     // pre-swizzled src chunk

  // hoisted LDS read offsets (elements)
  int koff[2][4], vbase[8], poff[2], vslot8[2];
#pragma unroll
  for (int kf = 0; kf < 2; ++kf)
#pragma unroll
    for (int c = 0; c < 4; ++c)
      koff[kf][c] = (kf * 16 + m) * 128 + (((c * 4 + q) ^ m) & 15) * 8;
#pragma unroll
  for (int f = 0; f < 8; ++f) vbase[f] = (f * 16 + m) * 64;
  vslot8[0] = ((q ^ (m & 7)) & 7) * 8;
  vslot8[1] = (((4 + q) ^ (m & 7)) & 7) * 8;
#pragma unroll
  for (int qf = 0; qf < 2; ++qf) poff[qf] = (qf * 16 + m) * 40 + q * 8;

#define ATTN_STAGE(buf, kb0)                                                  \
  do {                                                                        \
    _Pragma("unroll")                                                         \
    for (int i2 = 0; i2 < 4; ++i2)                                            \
      gload16(kptr + (size_t)((kb0) + i2 * 16 + kKeyR) * QKV_ + kSrcO,        \
              &Ks[buf][(i2 * 256 + tid) * 8]);                                \
    _Pragma("unroll")                                                         \
    for (int i2 = 0; i2 < 4; ++i2)                                            \
      gload16(vtptr + (size_t)(i2 * 32 + vDR) * T_ + (kb0) + vSrcO,           \
              &Vs[buf][(i2 * 256 + tid) * 8]);                                \
  } while (0)

#pragma unroll 1
  for (int ti = 0; ti < 2; ++ti) {
    const int qb = ((ti == 0) ? (15 - (int)blockIdx.x) : (int)blockIdx.x) * 128;
    const int qbw = qb + w * 32;
    const int nk = (qb >> 6) + 2;  // 64-key tiles covering keys 0..qb+127

    // Q fragments (B-operand)
    bf16x8 aq[2][4];
#pragma unroll
    for (int qf = 0; qf < 2; ++qf)
#pragma unroll
      for (int c = 0; c < 4; ++c)
        aq[qf][c] = *(const bf16x8*)(qptr + (size_t)(qbw + qf * 16 + m) * QKV_ + c * 32 + q * 8);

    f32x4 o[2][8];
#pragma unroll
    for (int qf = 0; qf < 2; ++qf)
#pragma unroll
      for (int f = 0; f < 8; ++f) o[qf][f] = (f32x4){0.f, 0.f, 0.f, 0.f};
    float l_r[2] = {0.f, 0.f};  // lane-local partial; reduced in epilogue

    ATTN_STAGE(0, 0);  // prefetch tile 0

#pragma unroll 1
    for (int it = 0; it < nk; ++it) {
      const int kb = it << 6;
      __syncthreads();  // drains tile-it loads (issued one full iter ago)

      if (it + 1 < nk) ATTN_STAGE((it + 1) & 1, kb + 64);

#pragma unroll
      for (int s = 0; s < 2; ++s) {
        const int kbs = kb + s * 32;
        if (kbs > qbw + 31) continue;  // sub-tile fully masked for this wave
        const bf16_t* Kb = &Ks[it & 1][s * 4096];
        const bf16_t* Vb = Vs[it & 1];

        // ---- S^T = K . Q^T
        f32x4 S[2][2];
#pragma unroll
        for (int qf = 0; qf < 2; ++qf)
#pragma unroll
          for (int kf = 0; kf < 2; ++kf) S[qf][kf] = (f32x4){0.f, 0.f, 0.f, 0.f};
#pragma unroll
        for (int kf = 0; kf < 2; ++kf)
#pragma unroll
          for (int c = 0; c < 4; ++c) {
            bf16x8 ak = *(const bf16x8*)&Kb[koff[kf][c]];
            S[0][kf] = __builtin_amdgcn_mfma_f32_16x16x32_bf16(ak, aq[0][c], S[0][kf], 0, 0, 0);
            S[1][kf] = __builtin_amdgcn_mfma_f32_16x16x32_bf16(ak, aq[1][c], S[1][kf], 0, 0, 0);
          }

        const bool needmask = (kbs + 31) > qbw;
#pragma unroll
        for (int qf = 0; qf < 2; ++qf) {
          const int qrow = qbw + qf * 16 + m;
          if (needmask) {
#pragma unroll
            for (int kf = 0; kf < 2; ++kf)
#pragma unroll
              for (int r = 0; r < 4; ++r) {
                int key = kbs + kf * 16 + q * 4 + r;
                if (key > qrow) S[qf][kf][r] = -1e30f;
              }
          }
          float rs = 0.f;
#pragma unroll
          for (int kf = 0; kf < 2; ++kf)
#pragma unroll
            for (int r = 0; r < 4; ++r) {
              float p = exp2f(S[qf][kf][r]);
              S[qf][kf][r] = p;
              rs += p;
            }
          l_r[qf] += rs;  // lane-local; cross-lane reduce deferred to epilogue
#pragma unroll
          for (int kf = 0; kf < 2; ++kf) {
            bf16x4 pk = {(__bf16)S[qf][kf][0], (__bf16)S[qf][kf][1],
                         (__bf16)S[qf][kf][2], (__bf16)S[qf][kf][3]};
            *(bf16x4*)&Ps[w][(qf * 16 + m) * 40 + kf * 16 + q * 4] = pk;
          }
        }
        asm volatile("s_waitcnt lgkmcnt(0)" ::: "memory");

        // ---- PV: O^T += V^T . P^T
        bf16x8 Pb[2];
#pragma unroll
        for (int qf = 0; qf < 2; ++qf)
          Pb[qf] = *(const bf16x8*)&Ps[w][poff[qf]];
#pragma unroll
        for (int f = 0; f < 8; ++f) {
          bf16x8 av = *(const bf16x8*)&Vb[vbase[f] + vslot8[s]];
          o[0][f] = __builtin_amdgcn_mfma_f32_16x16x32_bf16(av, Pb[0], o[0][f], 0, 0, 0);
          o[1][f] = __builtin_amdgcn_mfma_f32_16x16x32_bf16(av, Pb[1], o[1][f], 0, 0, 0);
        }
      }
    }

    // ---- epilogue: y = o/l minus projection onto normalized v row
#pragma unroll
    for (int qf = 0; qf < 2; ++qf) {
      const int trow = qbw + qf * 16 + m;
      float lt = l_r[qf];
      lt += __shfl_xor(lt, 16);
      lt += __shfl_xor(lt, 32);
      const float linv = 1.f / lt;
      bf16x4 vv[8];
      float n2 = 0.f, dp = 0.f;
#pragma unroll
      for (int f = 0; f < 8; ++f) {
        vv[f] = *(const bf16x4*)(vptr + (size_t)trow * QKV_ + f * 16 + q * 4);
#pragma unroll
        for (int r = 0; r < 4; ++r) {
          float v = (float)vv[f][r];
          n2 += v * v;
          dp += o[qf][f][r] * linv * v;
        }
      }
      n2 += __shfl_xor(n2, 16); n2 += __shfl_xor(n2, 32);
      dp += __shfl_xor(dp, 16); dp += __shfl_xor(dp, 32);
      float d = fmaxf(sqrtf(n2), 1e-12f);
      float coef = dp / (d * d);
#pragma unroll
      for (int f = 0; f < 8; ++f) {
        bf16x4 yo;
#pragma unroll
        for (int r = 0; r < 4; ++r)
          yo[r] = (bf16_t)(o[qf][f][r] * linv - coef * (float)vv[f][r]);
        *(bf16x4*)(y + (size_t)(b * T_ + trow) * DIM_ + h * HD_ + f * 16 + q * 4) = yo;
      }
    }
    __syncthreads();  // protect K/V buffers before next q-tile's prefetch
  }
}

// ---------------------------------------------------------------------------
extern "C" void kernel_launch(void* const* d_in, const int* in_sizes, int n_in,
                              void* d_out, int out_size, void* d_ws, size_t ws_size,
                              hipStream_t stream) {
  const float* x = (const float*)d_in[0];
  const float* Wq = (const float*)d_in[1];
  const float* Wk = (const float*)d_in[2];
  const float* Wv = (const float*)d_in[3];
  const float* Wp = (const float*)d_in[4];
  const float* qg = (const float*)d_in[5];

  bf16_t* xbf = (bf16_t*)d_ws;                        // 8192*2048
  bf16_t* wqkv = xbf + (size_t)8192 * 2048;           // 3072*2048
  bf16_t* wproj = wqkv + (size_t)3072 * 2048;         // 2048*2048
  bf16_t* qkv = wproj + (size_t)2048 * 2048;          // 8192*3072
  bf16_t* vt = qkv + (size_t)8192 * 3072;             // 16*128*2048
  bf16_t* ybf = xbf;                                  // reuse after gemm_qkv

  cvt_all<<<26624, 256, 0, stream>>>((const float4*)x, (const float4*)Wq,
                                     (const float4*)Wk, (const float4*)Wv,
                                     (const float4*)Wp, (bf16x4*)xbf,
                                     (bf16x4*)wqkv, (bf16x4*)wproj);
  gemm_qkv<<<dim3(24, 64), 256, 0, stream>>>(xbf, wqkv, qkv, vt, qg);
  attn_kernel<<<dim3(8, 16, 4), 256, 0, stream>>>(qkv, vt, ybf);
  gemm_bt<<<dim3(8, 32), 512, 0, stream>>>(ybf, wproj, d_out, 8192, 2048, 2048, 0);
}